// Round 1
// baseline (617.477 us; speedup 1.0000x reference)
//
#include <hip/hip_runtime.h>
#include <math.h>

#define D 4096
#define NSLOTS 128
#define TILE_Q 32
#define KC 64

// ---------------- Kernel A: EMA write into mem_new (ws) ----------------
// grid = NSLOTS blocks, 256 threads. Block s computes mem_new row s.
__global__ __launch_bounds__(256) void update_mem_kernel(
    const float* __restrict__ values, const float* __restrict__ memory,
    const float* __restrict__ gate_w, const float* __restrict__ gate_b,
    const int* __restrict__ layer_idx_p, const int* __restrict__ ptr_p,
    int T_W, float* __restrict__ ws_mem) {
  const int l = layer_idx_p[0];
  const int p = ptr_p[0];
  const int s = blockIdx.x;
  const int tid = threadIdx.x;

  int t0 = ((s - p) % NSLOTS + NSLOTS) % NSLOTS;
  bool written = (t0 < T_W);
  int t = written ? (t0 + ((T_W - 1 - t0) / NSLOTS) * NSLOTS) : 0; // last write wins

  const float* mrow = memory + ((size_t)l * NSLOTS + s) * D;
  float* orow = ws_mem + (size_t)s * D;

  if (!written) {
    for (int j = tid; j < D; j += blockDim.x) orow[j] = mrow[j];
    return;
  }

  const float* vrow = values + (size_t)t * D;
  const float* gw = gate_w + (size_t)l * D;

  // fp64 dot(values[t], gate_w[l])
  double acc = 0.0;
  for (int j = tid; j < D; j += blockDim.x)
    acc += (double)vrow[j] * (double)gw[j];
  for (int off = 32; off; off >>= 1) acc += __shfl_down(acc, off, 64);

  __shared__ double wsum[4];
  const int wid = tid >> 6, lane = tid & 63;
  if (lane == 0) wsum[wid] = acc;
  __syncthreads();
  double dot = 0.0;
  const int nw = blockDim.x >> 6;
  for (int w = 0; w < nw; w++) dot += wsum[w];

  const float x = (float)dot + gate_b[l];
  const float g = 1.0f / (1.0f + expf(-x));
  const float a = 0.1f * g;
  for (int j = tid; j < D; j += blockDim.x)
    orow[j] = a * vrow[j] + 0.9f * mrow[j];
}

// ---------------- Kernel B: scores = Q @ mem_new^T * scale (fp64 accum) ----
// grid = T_R/TILE_Q blocks of 256 threads. Block computes [TILE_Q x 128] tile.
// Thread (i = tid>>5, j = tid&31) owns queries 4i..4i+3 x slots 4j..4j+3.
__global__ __launch_bounds__(256) void scores_gemm_kernel(
    const float* __restrict__ queries, const float* __restrict__ ws_mem,
    float* __restrict__ ws_scores) {
  __shared__ float Qs[KC][TILE_Q];   // 8 KB
  __shared__ float Ms[KC][NSLOTS];   // 32 KB
  const int tid = threadIdx.x;
  const int j = tid & 31;
  const int i = tid >> 5;
  const int qbase = blockIdx.x * TILE_Q;

  double acc[4][4];
#pragma unroll
  for (int a = 0; a < 4; a++)
#pragma unroll
    for (int b = 0; b < 4; b++) acc[a][b] = 0.0;

  for (int k0 = 0; k0 < D; k0 += KC) {
    __syncthreads();
    // stage Q tile: 32 x 64 floats = 512 float4, 2 per thread
#pragma unroll
    for (int r = 0; r < 2; r++) {
      int e = tid + r * 256;           // float4 index
      int q = e >> 4;                  // 16 float4 per row
      int kk4 = e & 15;
      float4 v = *(const float4*)(queries + (size_t)(qbase + q) * D + k0 + kk4 * 4);
      Qs[kk4 * 4 + 0][q] = v.x; Qs[kk4 * 4 + 1][q] = v.y;
      Qs[kk4 * 4 + 2][q] = v.z; Qs[kk4 * 4 + 3][q] = v.w;
    }
    // stage M tile: 128 x 64 floats = 2048 float4, 8 per thread
#pragma unroll
    for (int r = 0; r < 8; r++) {
      int e = tid + r * 256;
      int s = e >> 4;
      int kk4 = e & 15;
      float4 v = *(const float4*)(ws_mem + (size_t)s * D + k0 + kk4 * 4);
      Ms[kk4 * 4 + 0][s] = v.x; Ms[kk4 * 4 + 1][s] = v.y;
      Ms[kk4 * 4 + 2][s] = v.z; Ms[kk4 * 4 + 3][s] = v.w;
    }
    __syncthreads();
#pragma unroll 8
    for (int kk = 0; kk < KC; kk++) {
      float4 qv = *(const float4*)&Qs[kk][i * 4];
      float4 mv = *(const float4*)&Ms[kk][j * 4];
      double qd[4] = {(double)qv.x, (double)qv.y, (double)qv.z, (double)qv.w};
      double md[4] = {(double)mv.x, (double)mv.y, (double)mv.z, (double)mv.w};
#pragma unroll
      for (int a = 0; a < 4; a++)
#pragma unroll
        for (int b = 0; b < 4; b++)
          acc[a][b] += qd[a] * md[b];
    }
  }

  const float scale = 0.015625f;  // 1/sqrt(4096), exact power of two
#pragma unroll
  for (int a = 0; a < 4; a++)
#pragma unroll
    for (int b = 0; b < 4; b++) {
      int q = qbase + i * 4 + a;
      int s = j * 4 + b;
      ws_scores[(size_t)q * NSLOTS + s] = (float)acc[a][b] * scale;
    }
}

// ---------------- Kernel C: per-row top-k -> softmax -> weighted gather ----
__device__ __forceinline__ unsigned mapf(float f) {
  unsigned u = __float_as_uint(f);
  return (u & 0x80000000u) ? ~u : (u | 0x80000000u);  // order-preserving
}

__global__ __launch_bounds__(256) void topk_out_kernel(
    const float* __restrict__ ws_scores, const float* __restrict__ ws_mem,
    const int* __restrict__ k_p, float* __restrict__ out) {
  const int row = blockIdx.x;
  const int tid = threadIdx.x;
  int k = k_p[0];
  if (k < 1) k = 1;
  if (k > NSLOTS) k = NSLOTS;

  __shared__ float sc[NSLOTS];
  __shared__ int topidx[NSLOTS];
  __shared__ float topv[NSLOTS];
  __shared__ float attw[NSLOTS];

  if (tid < NSLOTS) sc[tid] = ws_scores[(size_t)row * NSLOTS + tid];
  __syncthreads();

  for (int it = 0; it < k; it++) {
    if (tid < 64) {
      float v1 = sc[tid];
      float v2 = sc[tid + 64];
      // lexicographic key: (ordered value bits, 127-idx) -> max picks
      // highest value, ties broken toward the LOWER index (matches lax.top_k)
      unsigned long long k1 = ((unsigned long long)mapf(v1) << 32) | (unsigned)(NSLOTS - 1 - tid);
      unsigned long long k2 = ((unsigned long long)mapf(v2) << 32) | (unsigned)(NSLOTS - 1 - (tid + 64));
      unsigned long long key = (k1 > k2) ? k1 : k2;
      for (int off = 32; off; off >>= 1) {
        unsigned long long o = __shfl_xor(key, off, 64);
        if (o > key) key = o;
      }
      if (tid == 0) {
        int idx = NSLOTS - 1 - (int)(key & 0xffffffffULL);
        topidx[it] = idx;
        topv[it] = sc[idx];
        sc[idx] = -INFINITY;
      }
    }
    __syncthreads();
  }

  // softmax weights over the k selected scores (max is topv[0])
  if (tid < k) attw[tid] = expf(topv[tid] - topv[0]);
  __syncthreads();
  float ssum = 0.0f;
  for (int i2 = 0; i2 < k; i2++) ssum += attw[i2];
  const float inv = 1.0f / ssum;

  // out[row] = sum_i attn_i * mem_new[topidx_i]
  float* orow = out + (size_t)row * D;
#pragma unroll
  for (int c = 0; c < 4; c++) {
    int jj = (tid + c * 256) * 4;  // 256 threads * 4 floats * 4 chunks = 4096
    float4 acc = make_float4(0.f, 0.f, 0.f, 0.f);
    for (int i2 = 0; i2 < k; i2++) {
      const float w = attw[i2] * inv;
      const float4 mv = *(const float4*)(ws_mem + (size_t)topidx[i2] * D + jj);
      acc.x += w * mv.x; acc.y += w * mv.y; acc.z += w * mv.z; acc.w += w * mv.w;
    }
    *(float4*)(orow + jj) = acc;
  }
}

extern "C" void kernel_launch(void* const* d_in, const int* in_sizes, int n_in,
                              void* d_out, int out_size, void* d_ws, size_t ws_size,
                              hipStream_t stream) {
  const float* values  = (const float*)d_in[0];
  const float* queries = (const float*)d_in[1];
  const float* memory  = (const float*)d_in[2];
  const float* gate_w  = (const float*)d_in[3];
  const float* gate_b  = (const float*)d_in[4];
  const int* layer_idx = (const int*)d_in[5];
  const int* k_p       = (const int*)d_in[6];
  const int* ptr_p     = (const int*)d_in[7];

  const int T_W = in_sizes[0] / D;       // 128
  const int T_R = in_sizes[1] / D;       // 8192

  float* ws_mem    = (float*)d_ws;                     // [128][4096]  2 MiB
  float* ws_scores = ws_mem + (size_t)NSLOTS * D;      // [8192][128]  4 MiB

  update_mem_kernel<<<NSLOTS, 256, 0, stream>>>(values, memory, gate_w, gate_b,
                                                layer_idx, ptr_p, T_W, ws_mem);
  scores_gemm_kernel<<<T_R / TILE_Q, 256, 0, stream>>>(queries, ws_mem, ws_scores);
  topk_out_kernel<<<T_R, 256, 0, stream>>>(ws_scores, ws_mem, k_p, (float*)d_out);
}

// Round 3
// 513.520 us; speedup vs baseline: 1.2024x; 1.2024x over previous
//
#include <hip/hip_runtime.h>
#include <math.h>

#define D 4096
#define NSLOTS 128
#define EPS_RESCORE 2e-4f

typedef __attribute__((ext_vector_type(8))) short bf16x8;
typedef __attribute__((ext_vector_type(4))) float f32x4;

// ---------------- Kernel A: EMA write into mem_new (ws) ----------------
__global__ __launch_bounds__(256) void update_mem_kernel(
    const float* __restrict__ values, const float* __restrict__ memory,
    const float* __restrict__ gate_w, const float* __restrict__ gate_b,
    const int* __restrict__ layer_idx_p, const int* __restrict__ ptr_p,
    int T_W, float* __restrict__ ws_mem) {
  const int l = layer_idx_p[0];
  const int p = ptr_p[0];
  const int s = blockIdx.x;
  const int tid = threadIdx.x;

  int t0 = ((s - p) % NSLOTS + NSLOTS) % NSLOTS;
  bool written = (t0 < T_W);
  int t = written ? (t0 + ((T_W - 1 - t0) / NSLOTS) * NSLOTS) : 0; // last write wins

  const float* mrow = memory + ((size_t)l * NSLOTS + s) * D;
  float* orow = ws_mem + (size_t)s * D;

  if (!written) {
    for (int j = tid; j < D; j += blockDim.x) orow[j] = mrow[j];
    return;
  }

  const float* vrow = values + (size_t)t * D;
  const float* gw = gate_w + (size_t)l * D;

  double acc = 0.0;
  for (int j = tid; j < D; j += blockDim.x)
    acc += (double)vrow[j] * (double)gw[j];
  for (int off = 32; off; off >>= 1) acc += __shfl_down(acc, off, 64);

  __shared__ double wsum[4];
  const int wid = tid >> 6, lane = tid & 63;
  if (lane == 0) wsum[wid] = acc;
  __syncthreads();
  double dot = 0.0;
  const int nw = blockDim.x >> 6;
  for (int w = 0; w < nw; w++) dot += wsum[w];

  const float x = (float)dot + gate_b[l];
  const float g = 1.0f / (1.0f + expf(-x));
  const float a = 0.1f * g;
  for (int j = tid; j < D; j += blockDim.x)
    orow[j] = a * vrow[j] + 0.9f * mrow[j];
}

// ---------------- Kernel S: split fp32 -> bf16 hi + bf16 mid planes -------
__device__ __forceinline__ unsigned short bfrne(float x) {
  unsigned u = __float_as_uint(x);
  unsigned r = u + 0x7fffu + ((u >> 16) & 1u);   // round-to-nearest-even
  return (unsigned short)(r >> 16);
}

__global__ __launch_bounds__(256) void split_kernel(
    const float* __restrict__ queries, const float* __restrict__ ws_mem,
    unsigned short* __restrict__ Qh, unsigned short* __restrict__ Qm,
    unsigned short* __restrict__ Mh, unsigned short* __restrict__ Mm, int nq) {
  const size_t total_q = (size_t)nq * D / 4;       // float4 count
  const size_t total_m = (size_t)NSLOTS * D / 4;
  for (size_t i = (size_t)blockIdx.x * blockDim.x + threadIdx.x;
       i < total_q + total_m; i += (size_t)gridDim.x * blockDim.x) {
    const bool isq = (i < total_q);
    const float4 v = isq ? ((const float4*)queries)[i]
                         : ((const float4*)ws_mem)[i - total_q];
    unsigned short h0 = bfrne(v.x), h1 = bfrne(v.y), h2 = bfrne(v.z), h3 = bfrne(v.w);
    float f0 = __uint_as_float((unsigned)h0 << 16);
    float f1 = __uint_as_float((unsigned)h1 << 16);
    float f2 = __uint_as_float((unsigned)h2 << 16);
    float f3 = __uint_as_float((unsigned)h3 << 16);
    unsigned short m0 = bfrne(v.x - f0), m1 = bfrne(v.y - f1),
                   m2 = bfrne(v.z - f2), m3 = bfrne(v.w - f3);
    uint2 hp = make_uint2((unsigned)h0 | ((unsigned)h1 << 16),
                          (unsigned)h2 | ((unsigned)h3 << 16));
    uint2 mp = make_uint2((unsigned)m0 | ((unsigned)m1 << 16),
                          (unsigned)m2 | ((unsigned)m3 << 16));
    if (isq) { ((uint2*)Qh)[i] = hp; ((uint2*)Qm)[i] = mp; }
    else     { ((uint2*)Mh)[i - total_q] = hp; ((uint2*)Mm)[i - total_q] = mp; }
  }
}

// ---------------- Kernel B: scores via bf16-split MFMA (verified layout) ---
// Block: 256 thr (4 waves), tile = 16 q-rows x 128 slots. Wave w: slots
// [w*32, w*32+32). Direct global->VGPR fragment loads; M planes are L2-hot.
__global__ __launch_bounds__(256) void scores_gemm_split(
    const unsigned short* __restrict__ Qh, const unsigned short* __restrict__ Qm,
    const unsigned short* __restrict__ Mh, const unsigned short* __restrict__ Mm,
    float* __restrict__ ws_scores) {
  const int tid = threadIdx.x;
  const int lane = tid & 63;
  const int w = tid >> 6;
  const int fr = lane & 15;       // A row / B col / D col
  const int fo = lane >> 4;       // k-octet (8 bf16 = 16B)
  const int qbase = blockIdx.x * 16;

  const unsigned short* qh_p = Qh + (size_t)(qbase + fr) * D + fo * 8;
  const unsigned short* qm_p = Qm + (size_t)(qbase + fr) * D + fo * 8;
  const int s0 = w * 32 + fr;
  const unsigned short* mh0 = Mh + (size_t)s0 * D + fo * 8;
  const unsigned short* mm0 = Mm + (size_t)s0 * D + fo * 8;
  const unsigned short* mh1 = mh0 + (size_t)16 * D;
  const unsigned short* mm1 = mm0 + (size_t)16 * D;

  f32x4 acc0 = {0.f, 0.f, 0.f, 0.f};
  f32x4 acc1 = {0.f, 0.f, 0.f, 0.f};

#pragma unroll 4
  for (int k0 = 0; k0 < D; k0 += 32) {
    bf16x8 ah  = *(const bf16x8*)(qh_p + k0);
    bf16x8 am  = *(const bf16x8*)(qm_p + k0);
    bf16x8 bh0 = *(const bf16x8*)(mh0 + k0);
    bf16x8 bm0 = *(const bf16x8*)(mm0 + k0);
    bf16x8 bh1 = *(const bf16x8*)(mh1 + k0);
    bf16x8 bm1 = *(const bf16x8*)(mm1 + k0);
    // small cross terms first, then hi*hi (all into same fp32 acc)
    acc0 = __builtin_amdgcn_mfma_f32_16x16x32_bf16(am, bh0, acc0, 0, 0, 0);
    acc0 = __builtin_amdgcn_mfma_f32_16x16x32_bf16(ah, bm0, acc0, 0, 0, 0);
    acc0 = __builtin_amdgcn_mfma_f32_16x16x32_bf16(ah, bh0, acc0, 0, 0, 0);
    acc1 = __builtin_amdgcn_mfma_f32_16x16x32_bf16(am, bh1, acc1, 0, 0, 0);
    acc1 = __builtin_amdgcn_mfma_f32_16x16x32_bf16(ah, bm1, acc1, 0, 0, 0);
    acc1 = __builtin_amdgcn_mfma_f32_16x16x32_bf16(ah, bh1, acc1, 0, 0, 0);
  }

  const float scale = 0.015625f;  // 1/sqrt(4096)
#pragma unroll
  for (int r = 0; r < 4; r++) {
    int q = qbase + fo * 4 + r;          // D row = (lane>>4)*4 + reg
    int s = w * 32 + fr;                 // D col = lane&15
    ws_scores[(size_t)q * NSLOTS + s]      = acc0[r] * scale;
    ws_scores[(size_t)q * NSLOTS + s + 16] = acc1[r] * scale;
  }
}

// ---------------- Fallback: fp64-vector GEMM (round-1, proven) ------------
#define TILE_Q 32
#define KC 64
__global__ __launch_bounds__(256) void scores_gemm_f64vec(
    const float* __restrict__ queries, const float* __restrict__ ws_mem,
    float* __restrict__ ws_scores) {
  __shared__ float Qs[KC][TILE_Q];
  __shared__ float Ms[KC][NSLOTS];
  const int tid = threadIdx.x;
  const int j = tid & 31;
  const int i = tid >> 5;
  const int qbase = blockIdx.x * TILE_Q;

  double acc[4][4];
#pragma unroll
  for (int a = 0; a < 4; a++)
#pragma unroll
    for (int b = 0; b < 4; b++) acc[a][b] = 0.0;

  for (int k0 = 0; k0 < D; k0 += KC) {
    __syncthreads();
#pragma unroll
    for (int r = 0; r < 2; r++) {
      int e = tid + r * 256;
      int q = e >> 4, kk4 = e & 15;
      float4 v = *(const float4*)(queries + (size_t)(qbase + q) * D + k0 + kk4 * 4);
      Qs[kk4 * 4 + 0][q] = v.x; Qs[kk4 * 4 + 1][q] = v.y;
      Qs[kk4 * 4 + 2][q] = v.z; Qs[kk4 * 4 + 3][q] = v.w;
    }
#pragma unroll
    for (int r = 0; r < 8; r++) {
      int e = tid + r * 256;
      int s = e >> 4, kk4 = e & 15;
      float4 v = *(const float4*)(ws_mem + (size_t)s * D + k0 + kk4 * 4);
      Ms[kk4 * 4 + 0][s] = v.x; Ms[kk4 * 4 + 1][s] = v.y;
      Ms[kk4 * 4 + 2][s] = v.z; Ms[kk4 * 4 + 3][s] = v.w;
    }
    __syncthreads();
#pragma unroll 8
    for (int kk = 0; kk < KC; kk++) {
      float4 qv = *(const float4*)&Qs[kk][i * 4];
      float4 mv = *(const float4*)&Ms[kk][j * 4];
      double qd[4] = {qv.x, qv.y, qv.z, qv.w};
      double md[4] = {mv.x, mv.y, mv.z, mv.w};
#pragma unroll
      for (int a = 0; a < 4; a++)
#pragma unroll
        for (int b = 0; b < 4; b++) acc[a][b] += qd[a] * md[b];
    }
  }
  const float scale = 0.015625f;
#pragma unroll
  for (int a = 0; a < 4; a++)
#pragma unroll
    for (int b = 0; b < 4; b++)
      ws_scores[(size_t)(qbase + i * 4 + a) * NSLOTS + j * 4 + b] =
          (float)acc[a][b] * scale;
}

// ---------------- Kernel C: top-k (+fp64 rescore net) -> softmax -> out ----
__device__ __forceinline__ unsigned mapf(float f) {
  unsigned u = __float_as_uint(f);
  return (u & 0x80000000u) ? ~u : (u | 0x80000000u);
}

__device__ __forceinline__ void select_topk(float* sc, int* topidx, float* topv,
                                            int ksel, int tid) {
  for (int it = 0; it < ksel; it++) {
    if (tid < 64) {
      float v1 = sc[tid], v2 = sc[tid + 64];
      unsigned long long k1 =
          ((unsigned long long)mapf(v1) << 32) | (unsigned)(NSLOTS - 1 - tid);
      unsigned long long k2 =
          ((unsigned long long)mapf(v2) << 32) | (unsigned)(NSLOTS - 1 - (tid + 64));
      unsigned long long key = (k1 > k2) ? k1 : k2;
      for (int off = 32; off; off >>= 1) {
        unsigned long long o = __shfl_xor(key, off, 64);
        if (o > key) key = o;
      }
      if (tid == 0) {
        int idx = NSLOTS - 1 - (int)(key & 0xffffffffULL);
        topidx[it] = idx;
        topv[it] = sc[idx];
        sc[idx] = -INFINITY;
      }
    }
    __syncthreads();
  }
}

__global__ __launch_bounds__(256) void topk_out_kernel(
    const float* __restrict__ ws_scores, const float* __restrict__ ws_mem,
    const float* __restrict__ queries, const int* __restrict__ k_p,
    float* __restrict__ out) {
  const int row = blockIdx.x;
  const int tid = threadIdx.x;
  int k = k_p[0];
  if (k < 1) k = 1;
  if (k > NSLOTS) k = NSLOTS;

  __shared__ float sc[NSLOTS];
  __shared__ int topidx[NSLOTS + 1];
  __shared__ float topv[NSLOTS + 1];
  __shared__ float attw[NSLOTS];
  __shared__ float qrow[D];        // 16 KB
  __shared__ int trig_s;

  if (tid < NSLOTS) sc[tid] = ws_scores[(size_t)row * NSLOTS + tid];
  __syncthreads();

  const int ksel = (k + 1 <= NSLOTS) ? (k + 1) : NSLOTS;
  select_topk(sc, topidx, topv, ksel, tid);

  if (tid == 0)
    trig_s = (ksel > k) && (topv[k - 1] - topv[k] < EPS_RESCORE);
  __syncthreads();

  if (trig_s) {
    // exact fp64 rescore of all 128 slots for this row
    for (int j4 = tid; j4 < D / 4; j4 += 256)
      ((float4*)qrow)[j4] = ((const float4*)(queries + (size_t)row * D))[j4];
    __syncthreads();
    const int slot = tid >> 1, half = tid & 1;
    const float* mrow = ws_mem + (size_t)slot * D + half * 2048;
    const float* qp = qrow + half * 2048;
    double acc = 0.0;
    for (int jj = 0; jj < 2048; jj += 4) {
      acc += (double)qp[jj + 0] * (double)mrow[jj + 0];
      acc += (double)qp[jj + 1] * (double)mrow[jj + 1];
      acc += (double)qp[jj + 2] * (double)mrow[jj + 2];
      acc += (double)qp[jj + 3] * (double)mrow[jj + 3];
    }
    acc += __shfl_xor(acc, 1, 64);
    if (half == 0) sc[slot] = (float)(acc * 0.015625);
    __syncthreads();
    select_topk(sc, topidx, topv, k, tid);
  }

  if (tid < k) attw[tid] = expf(topv[tid] - topv[0]);
  __syncthreads();
  float ssum = 0.0f;
  for (int i2 = 0; i2 < k; i2++) ssum += attw[i2];
  const float inv = 1.0f / ssum;

  float* orow = out + (size_t)row * D;
#pragma unroll
  for (int c = 0; c < 4; c++) {
    int jj = (tid + c * 256) * 4;
    float4 acc = make_float4(0.f, 0.f, 0.f, 0.f);
    for (int i2 = 0; i2 < k; i2++) {
      const float wgt = attw[i2] * inv;
      const float4 mv = *(const float4*)(ws_mem + (size_t)topidx[i2] * D + jj);
      acc.x += wgt * mv.x; acc.y += wgt * mv.y;
      acc.z += wgt * mv.z; acc.w += wgt * mv.w;
    }
    *(float4*)(orow + jj) = acc;
  }
}

extern "C" void kernel_launch(void* const* d_in, const int* in_sizes, int n_in,
                              void* d_out, int out_size, void* d_ws, size_t ws_size,
                              hipStream_t stream) {
  const float* values  = (const float*)d_in[0];
  const float* queries = (const float*)d_in[1];
  const float* memory  = (const float*)d_in[2];
  const float* gate_w  = (const float*)d_in[3];
  const float* gate_b  = (const float*)d_in[4];
  const int* layer_idx = (const int*)d_in[5];
  const int* k_p       = (const int*)d_in[6];
  const int* ptr_p     = (const int*)d_in[7];

  const int T_W = in_sizes[0] / D;       // 128
  const int T_R = in_sizes[1] / D;       // 8192

  float* ws_mem    = (float*)d_ws;                            // 2 MiB
  float* ws_scores = ws_mem + (size_t)NSLOTS * D;             // 4 MiB
  unsigned short* Mh = (unsigned short*)(ws_scores + (size_t)T_R * NSLOTS);
  unsigned short* Mm = Mh + (size_t)NSLOTS * D;               // 1 MiB each
  unsigned short* Qh = Mm + (size_t)NSLOTS * D;               // 64 MiB
  unsigned short* Qm = Qh + (size_t)T_R * D;                  // 64 MiB

  const size_t need = (size_t)(Qm + (size_t)T_R * D - (unsigned short*)d_ws) * 2;

  update_mem_kernel<<<NSLOTS, 256, 0, stream>>>(values, memory, gate_w, gate_b,
                                                layer_idx, ptr_p, T_W, ws_mem);
  if (ws_size >= need) {
    split_kernel<<<2048, 256, 0, stream>>>(queries, ws_mem, Qh, Qm, Mh, Mm, T_R);
    scores_gemm_split<<<T_R / 16, 256, 0, stream>>>(Qh, Qm, Mh, Mm, ws_scores);
  } else {
    scores_gemm_f64vec<<<T_R / TILE_Q, 256, 0, stream>>>(queries, ws_mem, ws_scores);
  }
  topk_out_kernel<<<T_R, 256, 0, stream>>>(ws_scores, ws_mem, queries, k_p,
                                           (float*)d_out);
}

// Round 4
// 359.518 us; speedup vs baseline: 1.7175x; 1.4284x over previous
//
#include <hip/hip_runtime.h>
#include <math.h>

#define D 4096
#define NSLOTS 128
#define EPS_TRIG 5e-5f
#define WIN 2e-5f

typedef __attribute__((ext_vector_type(8))) short bf16x8;
typedef __attribute__((ext_vector_type(4))) float f32x4;

union BV { bf16x8 v; unsigned u[4]; };

__device__ __forceinline__ unsigned short bfrne(float x) {
  unsigned u = __float_as_uint(x);
  unsigned r = u + 0x7fffu + ((u >> 16) & 1u);   // round-to-nearest-even
  return (unsigned short)(r >> 16);
}

// ---- Kernel A: EMA write + produce M bf16 hi/mid planes (row-major + T) ----
__global__ __launch_bounds__(256) void update_mem_kernel(
    const float* __restrict__ values, const float* __restrict__ memory,
    const float* __restrict__ gate_w, const float* __restrict__ gate_b,
    const int* __restrict__ layer_idx_p, const int* __restrict__ ptr_p,
    int T_W, float* __restrict__ ws_mem,
    unsigned short* __restrict__ Mh, unsigned short* __restrict__ Mm,
    unsigned short* __restrict__ Mth, unsigned short* __restrict__ Mtm) {
  const int l = layer_idx_p[0], p = ptr_p[0], s = blockIdx.x, tid = threadIdx.x;
  int t0 = ((s - p) % NSLOTS + NSLOTS) % NSLOTS;
  const bool written = (t0 < T_W);
  const int t = written ? (t0 + ((T_W - 1 - t0) / NSLOTS) * NSLOTS) : 0; // last write wins
  const float* mrow = memory + ((size_t)l * NSLOTS + s) * D;
  const float* vrow = values + (size_t)t * D;

  float acoef = 0.f, bcoef = 1.0f;
  if (written) {
    const float* gw = gate_w + (size_t)l * D;
    double acc = 0.0;
    for (int j = tid; j < D; j += 256)
      acc += (double)vrow[j] * (double)gw[j];
    for (int off = 32; off; off >>= 1) acc += __shfl_down(acc, off, 64);
    __shared__ double wsum[4];
    if ((tid & 63) == 0) wsum[tid >> 6] = acc;
    __syncthreads();
    double dot = wsum[0] + wsum[1] + wsum[2] + wsum[3];
    float x = (float)dot + gate_b[l];
    float g = 1.0f / (1.0f + expf(-x));
    acoef = 0.1f * g; bcoef = 0.9f;
  }

  for (int j4 = tid; j4 < D / 4; j4 += 256) {
    float4 mv = ((const float4*)mrow)[j4];
    float4 vv = make_float4(0.f, 0.f, 0.f, 0.f);
    if (written) vv = ((const float4*)vrow)[j4];
    float ov[4];
    ov[0] = acoef * vv.x + bcoef * mv.x;
    ov[1] = acoef * vv.y + bcoef * mv.y;
    ov[2] = acoef * vv.z + bcoef * mv.z;
    ov[3] = acoef * vv.w + bcoef * mv.w;
    ((float4*)(ws_mem + (size_t)s * D))[j4] =
        make_float4(ov[0], ov[1], ov[2], ov[3]);
    unsigned short h[4], md[4];
#pragma unroll
    for (int e = 0; e < 4; ++e) {
      h[e] = bfrne(ov[e]);
      float f = __uint_as_float((unsigned)h[e] << 16);
      md[e] = bfrne(ov[e] - f);
    }
    uint2 hp = make_uint2((unsigned)h[0] | ((unsigned)h[1] << 16),
                          (unsigned)h[2] | ((unsigned)h[3] << 16));
    uint2 mp = make_uint2((unsigned)md[0] | ((unsigned)md[1] << 16),
                          (unsigned)md[2] | ((unsigned)md[3] << 16));
    ((uint2*)Mh)[(size_t)s * (D / 4) + j4] = hp;
    ((uint2*)Mm)[(size_t)s * (D / 4) + j4] = mp;
#pragma unroll
    for (int e = 0; e < 4; ++e) {
      Mth[(size_t)(j4 * 4 + e) * NSLOTS + s] = h[e];
      Mtm[(size_t)(j4 * 4 + e) * NSLOTS + s] = md[e];
    }
  }
}

// ---- Kernel B: scores = Q @ mem^T * scale, bf16-split MFMA, in-reg Q split ----
// 512 blocks x 256thr; block tile 16 q-rows x 128 slots; wave w: slots w*32..+32.
__global__ __launch_bounds__(256) void scores_kernel(
    const float* __restrict__ queries, const unsigned short* __restrict__ Mh,
    const unsigned short* __restrict__ Mm, float* __restrict__ ws_scores) {
  const int tid = threadIdx.x, lane = tid & 63, w = tid >> 6;
  const int fr = lane & 15, fo = lane >> 4;
  const int qbase = blockIdx.x * 16;
  const float* qp = queries + (size_t)(qbase + fr) * D + fo * 8;
  const int s0 = w * 32 + fr;
  const unsigned short* mh0 = Mh + (size_t)s0 * D + fo * 8;
  const unsigned short* mm0 = Mm + (size_t)s0 * D + fo * 8;
  const unsigned short* mh1 = mh0 + (size_t)16 * D;
  const unsigned short* mm1 = mm0 + (size_t)16 * D;

  f32x4 acc0 = {0.f, 0.f, 0.f, 0.f};
  f32x4 acc1 = {0.f, 0.f, 0.f, 0.f};

#pragma unroll 2
  for (int k0 = 0; k0 < D; k0 += 32) {
    float4 qa = *(const float4*)(qp + k0);
    float4 qb = *(const float4*)(qp + k0 + 4);
    float qf[8] = {qa.x, qa.y, qa.z, qa.w, qb.x, qb.y, qb.z, qb.w};
    BV ah, am;
#pragma unroll
    for (int i = 0; i < 4; ++i) {
      unsigned u0 = __float_as_uint(qf[2 * i]);
      unsigned u1 = __float_as_uint(qf[2 * i + 1]);
      ah.u[i] = (u0 >> 16) | (u1 & 0xffff0000u);     // truncated hi
      float f0 = __uint_as_float(u0 & 0xffff0000u);
      float f1 = __uint_as_float(u1 & 0xffff0000u);
      unsigned d0 = __float_as_uint(qf[2 * i] - f0);
      unsigned d1 = __float_as_uint(qf[2 * i + 1] - f1);
      am.u[i] = (d0 >> 16) | (d1 & 0xffff0000u);     // truncated mid
    }
    bf16x8 bh0 = *(const bf16x8*)(mh0 + k0);
    bf16x8 bm0 = *(const bf16x8*)(mm0 + k0);
    bf16x8 bh1 = *(const bf16x8*)(mh1 + k0);
    bf16x8 bm1 = *(const bf16x8*)(mm1 + k0);
    acc0 = __builtin_amdgcn_mfma_f32_16x16x32_bf16(am.v, bh0, acc0, 0, 0, 0);
    acc0 = __builtin_amdgcn_mfma_f32_16x16x32_bf16(ah.v, bm0, acc0, 0, 0, 0);
    acc0 = __builtin_amdgcn_mfma_f32_16x16x32_bf16(ah.v, bh0, acc0, 0, 0, 0);
    acc1 = __builtin_amdgcn_mfma_f32_16x16x32_bf16(am.v, bh1, acc1, 0, 0, 0);
    acc1 = __builtin_amdgcn_mfma_f32_16x16x32_bf16(ah.v, bm1, acc1, 0, 0, 0);
    acc1 = __builtin_amdgcn_mfma_f32_16x16x32_bf16(ah.v, bh1, acc1, 0, 0, 0);
  }

  const float scale = 0.015625f;  // 1/sqrt(4096)
#pragma unroll
  for (int r = 0; r < 4; ++r) {
    int q = qbase + fo * 4 + r;
    int s = w * 32 + fr;
    ws_scores[(size_t)q * NSLOTS + s]      = acc0[r] * scale;
    ws_scores[(size_t)q * NSLOTS + s + 16] = acc1[r] * scale;
  }
}

// ---- Kernel C: wave-per-row top-k -> softmax -> write A bf16 hi/mid planes ----
__device__ __forceinline__ unsigned mapf(float f) {
  unsigned u = __float_as_uint(f);
  return (u & 0x80000000u) ? ~u : (u | 0x80000000u);
}
__device__ __forceinline__ float unmapf(unsigned u) {
  return __uint_as_float((u & 0x80000000u) ? (u & 0x7fffffffu) : ~u);
}

__device__ __forceinline__ void wave_select(
    float va, float vb, int l, int k, int iters,
    float &m, float &sum, bool &sela, bool &selb, float &vkm1, float &vkk) {
  m = 0.f; sum = 0.f; sela = false; selb = false; vkm1 = 0.f; vkk = -3.4e38f;
  for (int it = 0; it < iters; ++it) {
    unsigned long long ka =
        ((unsigned long long)mapf(va) << 32) | (unsigned)(127 - l);
    unsigned long long kb =
        ((unsigned long long)mapf(vb) << 32) | (unsigned)(63 - l);
    unsigned long long key = ka > kb ? ka : kb;
#pragma unroll
    for (int off = 32; off; off >>= 1) {
      unsigned long long o = __shfl_xor(key, off, 64);
      if (o > key) key = o;
    }
    int idx = 127 - (int)(unsigned)(key & 0xffffffffULL);
    float val = unmapf((unsigned)(key >> 32));
    if (it == 0) m = val;
    if (it < k) sum += expf(val - m);
    if (it == k - 1) vkm1 = val;
    if (it == k) vkk = val;
    if (idx == l) { sela = sela || (it < k); va = -INFINITY; }
    if (idx == l + 64) { selb = selb || (it < k); vb = -INFINITY; }
  }
}

__device__ __forceinline__ float rescore_slot(const float* __restrict__ qrow,
                                              const float* __restrict__ mrow,
                                              int l) {
  double acc = 0.0;
#pragma unroll 4
  for (int c = 0; c < 16; ++c) {
    int j = c * 256 + l * 4;
    float4 qv = *(const float4*)(qrow + j);
    float4 mv = *(const float4*)(mrow + j);
    acc += (double)qv.x * (double)mv.x;
    acc += (double)qv.y * (double)mv.y;
    acc += (double)qv.z * (double)mv.z;
    acc += (double)qv.w * (double)mv.w;
  }
#pragma unroll
  for (int off = 32; off; off >>= 1) acc += __shfl_xor(acc, off, 64);
  return (float)(acc * 0.015625);
}

__global__ __launch_bounds__(256) void topk_kernel(
    const float* __restrict__ ws_scores, const float* __restrict__ ws_mem,
    const float* __restrict__ queries, const int* __restrict__ k_p,
    unsigned short* __restrict__ Ah, unsigned short* __restrict__ Am) {
  const int w = threadIdx.x >> 6, l = threadIdx.x & 63;
  const int row = blockIdx.x * 4 + w;
  int k = k_p[0];
  if (k < 1) k = 1;
  if (k > NSLOTS) k = NSLOTS;
  const int ksel = (k < NSLOTS) ? k + 1 : k;

  float origa = ws_scores[(size_t)row * NSLOTS + l];
  float origb = ws_scores[(size_t)row * NSLOTS + 64 + l];

  float m, sum, vkm1, vkk;
  bool sela, selb;
  wave_select(origa, origb, l, k, ksel, m, sum, sela, selb, vkm1, vkk);

  if (ksel > k && (vkm1 - vkk) < EPS_TRIG) {
    // exact fp64 rescore of boundary-window slots only (set membership fix)
    const float* qrow = queries + (size_t)row * D;
    float lo = vkk - WIN, hi = vkm1 + WIN;
    unsigned long long ba = __ballot(origa >= lo && origa <= hi);
    unsigned long long bb = __ballot(origb >= lo && origb <= hi);
    while (ba) {
      int s = __ffsll(ba) - 1; ba &= ba - 1;
      float ex = rescore_slot(qrow, ws_mem + (size_t)s * D, l);
      if (l == s) origa = ex;
    }
    while (bb) {
      int s = __ffsll(bb) - 1; bb &= bb - 1;
      float ex = rescore_slot(qrow, ws_mem + (size_t)(s + 64) * D, l);
      if (l == s) origb = ex;
    }
    wave_select(origa, origb, l, k, k, m, sum, sela, selb, vkm1, vkk);
  }

  const float inv = 1.0f / sum;
  float wa = sela ? expf(origa - m) * inv : 0.f;
  float wb = selb ? expf(origb - m) * inv : 0.f;

  unsigned short ha = bfrne(wa);
  unsigned short ma = bfrne(wa - __uint_as_float((unsigned)ha << 16));
  unsigned short hb = bfrne(wb);
  unsigned short mb = bfrne(wb - __uint_as_float((unsigned)hb << 16));
  Ah[(size_t)row * NSLOTS + l] = ha;
  Am[(size_t)row * NSLOTS + l] = ma;
  Ah[(size_t)row * NSLOTS + 64 + l] = hb;
  Am[(size_t)row * NSLOTS + 64 + l] = mb;
}

// ---- Kernel D: out = A @ mem_new as dense bf16-split GEMM (K=128) ----
// grid 4096: rowblk(128) x colblk(32); block 64 rows x 128 cols; wave: 16x128.
__global__ __launch_bounds__(256) void gather_kernel(
    const unsigned short* __restrict__ Ah, const unsigned short* __restrict__ Am,
    const unsigned short* __restrict__ Mth, const unsigned short* __restrict__ Mtm,
    float* __restrict__ out) {
  const int tid = threadIdx.x, lane = tid & 63, w = tid >> 6;
  const int fr = lane & 15, fo = lane >> 4;
  const int rowblk = blockIdx.x >> 5, colblk = blockIdx.x & 31;
  const int r0 = rowblk * 64 + w * 16;

  const unsigned short* ap_h = Ah + (size_t)(r0 + fr) * NSLOTS + fo * 8;
  const unsigned short* ap_m = Am + (size_t)(r0 + fr) * NSLOTS + fo * 8;
  bf16x8 a_h[4], a_m[4];
#pragma unroll
  for (int c = 0; c < 4; ++c) {
    a_h[c] = *(const bf16x8*)(ap_h + c * 32);
    a_m[c] = *(const bf16x8*)(ap_m + c * 32);
  }

#pragma unroll 2
  for (int ct = 0; ct < 8; ++ct) {
    const int col = colblk * 128 + ct * 16 + fr;
    const unsigned short* bp_h = Mth + (size_t)col * NSLOTS + fo * 8;
    const unsigned short* bp_m = Mtm + (size_t)col * NSLOTS + fo * 8;
    f32x4 acc = {0.f, 0.f, 0.f, 0.f};
#pragma unroll
    for (int c = 0; c < 4; ++c) {
      bf16x8 bh = *(const bf16x8*)(bp_h + c * 32);
      bf16x8 bm = *(const bf16x8*)(bp_m + c * 32);
      acc = __builtin_amdgcn_mfma_f32_16x16x32_bf16(a_m[c], bh, acc, 0, 0, 0);
      acc = __builtin_amdgcn_mfma_f32_16x16x32_bf16(a_h[c], bm, acc, 0, 0, 0);
      acc = __builtin_amdgcn_mfma_f32_16x16x32_bf16(a_h[c], bh, acc, 0, 0, 0);
    }
#pragma unroll
    for (int r = 0; r < 4; ++r)
      out[(size_t)(r0 + fo * 4 + r) * D + col] = acc[r];
  }
}

extern "C" void kernel_launch(void* const* d_in, const int* in_sizes, int n_in,
                              void* d_out, int out_size, void* d_ws, size_t ws_size,
                              hipStream_t stream) {
  const float* values  = (const float*)d_in[0];
  const float* queries = (const float*)d_in[1];
  const float* memory  = (const float*)d_in[2];
  const float* gate_w  = (const float*)d_in[3];
  const float* gate_b  = (const float*)d_in[4];
  const int* layer_idx = (const int*)d_in[5];
  const int* k_p       = (const int*)d_in[6];
  const int* ptr_p     = (const int*)d_in[7];

  const int T_W = in_sizes[0] / D;   // 128
  const int T_R = in_sizes[1] / D;   // 8192

  float* ws_mem    = (float*)d_ws;                           // 2 MiB
  float* ws_scores = ws_mem + (size_t)NSLOTS * D;            // 4 MiB
  unsigned short* Mh  = (unsigned short*)(ws_scores + (size_t)T_R * NSLOTS);
  unsigned short* Mm  = Mh  + (size_t)NSLOTS * D;            // 1 MiB each
  unsigned short* Mth = Mm  + (size_t)NSLOTS * D;
  unsigned short* Mtm = Mth + (size_t)NSLOTS * D;
  unsigned short* Ah  = Mtm + (size_t)NSLOTS * D;            // 2 MiB each
  unsigned short* Am  = Ah  + (size_t)T_R * NSLOTS;

  update_mem_kernel<<<NSLOTS, 256, 0, stream>>>(
      values, memory, gate_w, gate_b, layer_idx, ptr_p, T_W,
      ws_mem, Mh, Mm, Mth, Mtm);
  scores_kernel<<<T_R / 16, 256, 0, stream>>>(queries, Mh, Mm, ws_scores);
  topk_kernel<<<T_R / 4, 256, 0, stream>>>(ws_scores, ws_mem, queries, k_p,
                                           Ah, Am);
  gather_kernel<<<(T_R / 64) * 32, 256, 0, stream>>>(Ah, Am, Mth, Mtm,
                                                     (float*)d_out);
}

// Round 5
// 322.105 us; speedup vs baseline: 1.9170x; 1.1162x over previous
//
#include <hip/hip_runtime.h>
#include <math.h>

#define D 4096
#define NSLOTS 128
#define EPS_TRIG 5e-5f
#define WIN 2e-5f

typedef __attribute__((ext_vector_type(8))) short bf16x8;
typedef __attribute__((ext_vector_type(4))) float f32x4;

union BV { bf16x8 v; unsigned u[4]; };

__device__ __forceinline__ unsigned short bfrne(float x) {
  unsigned u = __float_as_uint(x);
  unsigned r = u + 0x7fffu + ((u >> 16) & 1u);   // round-to-nearest-even
  return (unsigned short)(r >> 16);
}

// ---- Kernel A: EMA write + produce M bf16 hi/mid planes (row-major + T) ----
__global__ __launch_bounds__(256) void update_mem_kernel(
    const float* __restrict__ values, const float* __restrict__ memory,
    const float* __restrict__ gate_w, const float* __restrict__ gate_b,
    const int* __restrict__ layer_idx_p, const int* __restrict__ ptr_p,
    int T_W, float* __restrict__ ws_mem,
    unsigned short* __restrict__ Mh, unsigned short* __restrict__ Mm,
    unsigned short* __restrict__ Mth, unsigned short* __restrict__ Mtm) {
  const int l = layer_idx_p[0], p = ptr_p[0], s = blockIdx.x, tid = threadIdx.x;
  int t0 = ((s - p) % NSLOTS + NSLOTS) % NSLOTS;
  const bool written = (t0 < T_W);
  const int t = written ? (t0 + ((T_W - 1 - t0) / NSLOTS) * NSLOTS) : 0; // last write wins
  const float* mrow = memory + ((size_t)l * NSLOTS + s) * D;
  const float* vrow = values + (size_t)t * D;

  float acoef = 0.f, bcoef = 1.0f;
  if (written) {
    const float* gw = gate_w + (size_t)l * D;
    double acc = 0.0;
    for (int j = tid; j < D; j += 256)
      acc += (double)vrow[j] * (double)gw[j];
    for (int off = 32; off; off >>= 1) acc += __shfl_down(acc, off, 64);
    __shared__ double wsum[4];
    if ((tid & 63) == 0) wsum[tid >> 6] = acc;
    __syncthreads();
    double dot = wsum[0] + wsum[1] + wsum[2] + wsum[3];
    float x = (float)dot + gate_b[l];
    float g = 1.0f / (1.0f + expf(-x));
    acoef = 0.1f * g; bcoef = 0.9f;
  }

  for (int j4 = tid; j4 < D / 4; j4 += 256) {
    float4 mv = ((const float4*)mrow)[j4];
    float4 vv = make_float4(0.f, 0.f, 0.f, 0.f);
    if (written) vv = ((const float4*)vrow)[j4];
    float ov[4];
    ov[0] = acoef * vv.x + bcoef * mv.x;
    ov[1] = acoef * vv.y + bcoef * mv.y;
    ov[2] = acoef * vv.z + bcoef * mv.z;
    ov[3] = acoef * vv.w + bcoef * mv.w;
    ((float4*)(ws_mem + (size_t)s * D))[j4] =
        make_float4(ov[0], ov[1], ov[2], ov[3]);
    unsigned short h[4], md[4];
#pragma unroll
    for (int e = 0; e < 4; ++e) {
      h[e] = bfrne(ov[e]);
      float f = __uint_as_float((unsigned)h[e] << 16);
      md[e] = bfrne(ov[e] - f);
    }
    uint2 hp = make_uint2((unsigned)h[0] | ((unsigned)h[1] << 16),
                          (unsigned)h[2] | ((unsigned)h[3] << 16));
    uint2 mp = make_uint2((unsigned)md[0] | ((unsigned)md[1] << 16),
                          (unsigned)md[2] | ((unsigned)md[3] << 16));
    ((uint2*)Mh)[(size_t)s * (D / 4) + j4] = hp;
    ((uint2*)Mm)[(size_t)s * (D / 4) + j4] = mp;
#pragma unroll
    for (int e = 0; e < 4; ++e) {
      Mth[(size_t)(j4 * 4 + e) * NSLOTS + s] = h[e];
      Mtm[(size_t)(j4 * 4 + e) * NSLOTS + s] = md[e];
    }
  }
}

// ---- Kernel B: scores = Q @ mem^T * scale (bf16-split MFMA, wave K-split) ----
// grid 512 x 256thr. Block tile: 16 q-rows x 128 slots. Wave w owns K-quarter
// [w*1024,(w+1)*1024) over ALL 128 slots -> 8 independent MFMA chains/wave.
// Epilogue: 4-wave partial-sum reduction through padded LDS.
__global__ __launch_bounds__(256) void scores_kernel(
    const float* __restrict__ queries, const unsigned short* __restrict__ Mh,
    const unsigned short* __restrict__ Mm, float* __restrict__ ws_scores) {
  __shared__ float red[4 * 16 * 130];   // 33.3 KB, stride 130 = conflict-free
  const int tid = threadIdx.x, lane = tid & 63, w = tid >> 6;
  const int fr = lane & 15, fo = lane >> 4;
  const int qbase = blockIdx.x * 16;
  const int kbase = w * 1024;

  const float* qp = queries + (size_t)(qbase + fr) * D + kbase + fo * 8;
  const unsigned short* mhp = Mh + (size_t)fr * D + kbase + fo * 8;
  const unsigned short* mmp = Mm + (size_t)fr * D + kbase + fo * 8;

  f32x4 acc[8];
#pragma unroll
  for (int g = 0; g < 8; ++g) acc[g] = (f32x4){0.f, 0.f, 0.f, 0.f};

  for (int k0 = 0; k0 < 1024; k0 += 32) {
    float4 qa = *(const float4*)(qp + k0);
    float4 qb = *(const float4*)(qp + k0 + 4);
    bf16x8 bh[8], bm[8];
#pragma unroll
    for (int g = 0; g < 8; ++g) {
      bh[g] = *(const bf16x8*)(mhp + (size_t)g * 16 * D + k0);
      bm[g] = *(const bf16x8*)(mmp + (size_t)g * 16 * D + k0);
    }
    float qf[8] = {qa.x, qa.y, qa.z, qa.w, qb.x, qb.y, qb.z, qb.w};
    BV ah, am;
#pragma unroll
    for (int i = 0; i < 4; ++i) {
      unsigned u0 = __float_as_uint(qf[2 * i]);
      unsigned u1 = __float_as_uint(qf[2 * i + 1]);
      ah.u[i] = (u0 >> 16) | (u1 & 0xffff0000u);     // truncated hi
      float f0 = __uint_as_float(u0 & 0xffff0000u);
      float f1 = __uint_as_float(u1 & 0xffff0000u);
      unsigned d0 = __float_as_uint(qf[2 * i] - f0);
      unsigned d1 = __float_as_uint(qf[2 * i + 1] - f1);
      am.u[i] = (d0 >> 16) | (d1 & 0xffff0000u);     // truncated mid
    }
#pragma unroll
    for (int g = 0; g < 8; ++g) {
      acc[g] = __builtin_amdgcn_mfma_f32_16x16x32_bf16(am.v, bh[g], acc[g], 0, 0, 0);
      acc[g] = __builtin_amdgcn_mfma_f32_16x16x32_bf16(ah.v, bm[g], acc[g], 0, 0, 0);
      acc[g] = __builtin_amdgcn_mfma_f32_16x16x32_bf16(ah.v, bh[g], acc[g], 0, 0, 0);
    }
  }

  // partials -> LDS
#pragma unroll
  for (int g = 0; g < 8; ++g)
#pragma unroll
    for (int r = 0; r < 4; ++r)
      red[(w * 16 + fo * 4 + r) * 130 + g * 16 + fr] = acc[g][r];
  __syncthreads();

  const float scale = 0.015625f;  // 1/sqrt(4096)
#pragma unroll
  for (int c = 0; c < 8; ++c) {
    int e = tid + c * 256;
    int i = e >> 7, j = e & 127;
    float v = red[(0 * 16 + i) * 130 + j] + red[(1 * 16 + i) * 130 + j] +
              red[(2 * 16 + i) * 130 + j] + red[(3 * 16 + i) * 130 + j];
    ws_scores[(size_t)(qbase + i) * NSLOTS + j] = v * scale;
  }
}

// ---- Kernel C: wave-per-row top-k -> softmax -> write A bf16 hi/mid planes ----
__device__ __forceinline__ unsigned mapf(float f) {
  unsigned u = __float_as_uint(f);
  return (u & 0x80000000u) ? ~u : (u | 0x80000000u);
}
__device__ __forceinline__ float unmapf(unsigned u) {
  return __uint_as_float((u & 0x80000000u) ? (u & 0x7fffffffu) : ~u);
}

__device__ __forceinline__ void wave_select(
    float va, float vb, int l, int k, int iters,
    float &m, float &sum, bool &sela, bool &selb, float &vkm1, float &vkk) {
  m = 0.f; sum = 0.f; sela = false; selb = false; vkm1 = 0.f; vkk = -3.4e38f;
  for (int it = 0; it < iters; ++it) {
    unsigned long long ka =
        ((unsigned long long)mapf(va) << 32) | (unsigned)(127 - l);
    unsigned long long kb =
        ((unsigned long long)mapf(vb) << 32) | (unsigned)(63 - l);
    unsigned long long key = ka > kb ? ka : kb;
#pragma unroll
    for (int off = 32; off; off >>= 1) {
      unsigned long long o = __shfl_xor(key, off, 64);
      if (o > key) key = o;
    }
    int idx = 127 - (int)(unsigned)(key & 0xffffffffULL);
    float val = unmapf((unsigned)(key >> 32));
    if (it == 0) m = val;
    if (it < k) sum += expf(val - m);
    if (it == k - 1) vkm1 = val;
    if (it == k) vkk = val;
    if (idx == l) { sela = sela || (it < k); va = -INFINITY; }
    if (idx == l + 64) { selb = selb || (it < k); vb = -INFINITY; }
  }
}

__device__ __forceinline__ float rescore_slot(const float* __restrict__ qrow,
                                              const float* __restrict__ mrow,
                                              int l) {
  double acc = 0.0;
#pragma unroll 4
  for (int c = 0; c < 16; ++c) {
    int j = c * 256 + l * 4;
    float4 qv = *(const float4*)(qrow + j);
    float4 mv = *(const float4*)(mrow + j);
    acc += (double)qv.x * (double)mv.x;
    acc += (double)qv.y * (double)mv.y;
    acc += (double)qv.z * (double)mv.z;
    acc += (double)qv.w * (double)mv.w;
  }
#pragma unroll
  for (int off = 32; off; off >>= 1) acc += __shfl_xor(acc, off, 64);
  return (float)(acc * 0.015625);
}

__global__ __launch_bounds__(256) void topk_kernel(
    const float* __restrict__ ws_scores, const float* __restrict__ ws_mem,
    const float* __restrict__ queries, const int* __restrict__ k_p,
    unsigned short* __restrict__ Ah, unsigned short* __restrict__ Am) {
  const int w = threadIdx.x >> 6, l = threadIdx.x & 63;
  const int row = blockIdx.x * 4 + w;
  int k = k_p[0];
  if (k < 1) k = 1;
  if (k > NSLOTS) k = NSLOTS;
  const int ksel = (k < NSLOTS) ? k + 1 : k;

  float origa = ws_scores[(size_t)row * NSLOTS + l];
  float origb = ws_scores[(size_t)row * NSLOTS + 64 + l];

  float m, sum, vkm1, vkk;
  bool sela, selb;
  wave_select(origa, origb, l, k, ksel, m, sum, sela, selb, vkm1, vkk);

  if (ksel > k && (vkm1 - vkk) < EPS_TRIG) {
    // exact fp64 rescore of boundary-window slots only (set membership fix)
    const float* qrow = queries + (size_t)row * D;
    float lo = vkk - WIN, hi = vkm1 + WIN;
    unsigned long long ba = __ballot(origa >= lo && origa <= hi);
    unsigned long long bb = __ballot(origb >= lo && origb <= hi);
    while (ba) {
      int s = __ffsll(ba) - 1; ba &= ba - 1;
      float ex = rescore_slot(qrow, ws_mem + (size_t)s * D, l);
      if (l == s) origa = ex;
    }
    while (bb) {
      int s = __ffsll(bb) - 1; bb &= bb - 1;
      float ex = rescore_slot(qrow, ws_mem + (size_t)(s + 64) * D, l);
      if (l == s) origb = ex;
    }
    wave_select(origa, origb, l, k, k, m, sum, sela, selb, vkm1, vkk);
  }

  const float inv = 1.0f / sum;
  float wa = sela ? expf(origa - m) * inv : 0.f;
  float wb = selb ? expf(origb - m) * inv : 0.f;

  unsigned short ha = bfrne(wa);
  unsigned short ma = bfrne(wa - __uint_as_float((unsigned)ha << 16));
  unsigned short hb = bfrne(wb);
  unsigned short mb = bfrne(wb - __uint_as_float((unsigned)hb << 16));
  Ah[(size_t)row * NSLOTS + l] = ha;
  Am[(size_t)row * NSLOTS + l] = ma;
  Ah[(size_t)row * NSLOTS + 64 + l] = hb;
  Am[(size_t)row * NSLOTS + 64 + l] = mb;
}

// ---- Kernel D: out = A @ mem_new as dense bf16-split GEMM (K=128) ----
// grid 4096: rowblk(128) x colblk(32); block 64 rows x 128 cols; wave: 16x128.
__global__ __launch_bounds__(256) void gather_kernel(
    const unsigned short* __restrict__ Ah, const unsigned short* __restrict__ Am,
    const unsigned short* __restrict__ Mth, const unsigned short* __restrict__ Mtm,
    float* __restrict__ out) {
  const int tid = threadIdx.x, lane = tid & 63, w = tid >> 6;
  const int fr = lane & 15, fo = lane >> 4;
  const int rowblk = blockIdx.x >> 5, colblk = blockIdx.x & 31;
  const int r0 = rowblk * 64 + w * 16;

  const unsigned short* ap_h = Ah + (size_t)(r0 + fr) * NSLOTS + fo * 8;
  const unsigned short* ap_m = Am + (size_t)(r0 + fr) * NSLOTS + fo * 8;
  bf16x8 a_h[4], a_m[4];
#pragma unroll
  for (int c = 0; c < 4; ++c) {
    a_h[c] = *(const bf16x8*)(ap_h + c * 32);
    a_m[c] = *(const bf16x8*)(ap_m + c * 32);
  }

#pragma unroll 2
  for (int ct = 0; ct < 8; ++ct) {
    const int col = colblk * 128 + ct * 16 + fr;
    const unsigned short* bp_h = Mth + (size_t)col * NSLOTS + fo * 8;
    const unsigned short* bp_m = Mtm + (size_t)col * NSLOTS + fo * 8;
    f32x4 acc = {0.f, 0.f, 0.f, 0.f};
#pragma unroll
    for (int c = 0; c < 4; ++c) {
      bf16x8 bh = *(const bf16x8*)(bp_h + c * 32);
      bf16x8 bm = *(const bf16x8*)(bp_m + c * 32);
      acc = __builtin_amdgcn_mfma_f32_16x16x32_bf16(a_m[c], bh, acc, 0, 0, 0);
      acc = __builtin_amdgcn_mfma_f32_16x16x32_bf16(a_h[c], bm, acc, 0, 0, 0);
      acc = __builtin_amdgcn_mfma_f32_16x16x32_bf16(a_h[c], bh, acc, 0, 0, 0);
    }
#pragma unroll
    for (int r = 0; r < 4; ++r)
      out[(size_t)(r0 + fo * 4 + r) * D + col] = acc[r];
  }
}

extern "C" void kernel_launch(void* const* d_in, const int* in_sizes, int n_in,
                              void* d_out, int out_size, void* d_ws, size_t ws_size,
                              hipStream_t stream) {
  const float* values  = (const float*)d_in[0];
  const float* queries = (const float*)d_in[1];
  const float* memory  = (const float*)d_in[2];
  const float* gate_w  = (const float*)d_in[3];
  const float* gate_b  = (const float*)d_in[4];
  const int* layer_idx = (const int*)d_in[5];
  const int* k_p       = (const int*)d_in[6];
  const int* ptr_p     = (const int*)d_in[7];

  const int T_W = in_sizes[0] / D;   // 128
  const int T_R = in_sizes[1] / D;   // 8192

  float* ws_mem    = (float*)d_ws;                           // 2 MiB
  float* ws_scores = ws_mem + (size_t)NSLOTS * D;            // 4 MiB
  unsigned short* Mh  = (unsigned short*)(ws_scores + (size_t)T_R * NSLOTS);
  unsigned short* Mm  = Mh  + (size_t)NSLOTS * D;            // 1 MiB each
  unsigned short* Mth = Mm  + (size_t)NSLOTS * D;
  unsigned short* Mtm = Mth + (size_t)NSLOTS * D;
  unsigned short* Ah  = Mtm + (size_t)NSLOTS * D;            // 2 MiB each
  unsigned short* Am  = Ah  + (size_t)T_R * NSLOTS;

  update_mem_kernel<<<NSLOTS, 256, 0, stream>>>(
      values, memory, gate_w, gate_b, layer_idx, ptr_p, T_W,
      ws_mem, Mh, Mm, Mth, Mtm);
  scores_kernel<<<T_R / 16, 256, 0, stream>>>(queries, Mh, Mm, ws_scores);
  topk_kernel<<<T_R / 4, 256, 0, stream>>>(ws_scores, ws_mem, queries, k_p,
                                           Ah, Am);
  gather_kernel<<<(T_R / 64) * 32, 256, 0, stream>>>(Ah, Am, Mth, Mtm,
                                                     (float*)d_out);
}

// Round 6
// 315.174 us; speedup vs baseline: 1.9592x; 1.0220x over previous
//
#include <hip/hip_runtime.h>
#include <math.h>

#define D 4096
#define NSLOTS 128
#define TR 8192
#define EPS_TRIG 5e-5f
#define WIN 2e-5f

typedef __attribute__((ext_vector_type(8))) short bf16x8;
typedef __attribute__((ext_vector_type(4))) float f32x4;

union BV { bf16x8 v; unsigned u[4]; };

__device__ __forceinline__ unsigned short bfrne(float x) {
  unsigned u = __float_as_uint(x);
  unsigned r = u + 0x7fffu + ((u >> 16) & 1u);   // round-to-nearest-even
  return (unsigned short)(r >> 16);
}

// ---- Kernel A: EMA write + produce M bf16 hi/mid planes (row-major + T) ----
__global__ __launch_bounds__(256) void update_mem_kernel(
    const float* __restrict__ values, const float* __restrict__ memory,
    const float* __restrict__ gate_w, const float* __restrict__ gate_b,
    const int* __restrict__ layer_idx_p, const int* __restrict__ ptr_p,
    int T_W, float* __restrict__ ws_mem,
    unsigned short* __restrict__ Mh, unsigned short* __restrict__ Mm,
    unsigned short* __restrict__ Mth, unsigned short* __restrict__ Mtm) {
  const int l = layer_idx_p[0], p = ptr_p[0], s = blockIdx.x, tid = threadIdx.x;
  int t0 = ((s - p) % NSLOTS + NSLOTS) % NSLOTS;
  const bool written = (t0 < T_W);
  const int t = written ? (t0 + ((T_W - 1 - t0) / NSLOTS) * NSLOTS) : 0; // last write wins
  const float* mrow = memory + ((size_t)l * NSLOTS + s) * D;
  const float* vrow = values + (size_t)t * D;

  float acoef = 0.f, bcoef = 1.0f;
  if (written) {
    const float* gw = gate_w + (size_t)l * D;
    double acc = 0.0;
    for (int j = tid; j < D; j += 256)
      acc += (double)vrow[j] * (double)gw[j];
    for (int off = 32; off; off >>= 1) acc += __shfl_down(acc, off, 64);
    __shared__ double wsum[4];
    if ((tid & 63) == 0) wsum[tid >> 6] = acc;
    __syncthreads();
    double dot = wsum[0] + wsum[1] + wsum[2] + wsum[3];
    float x = (float)dot + gate_b[l];
    float g = 1.0f / (1.0f + expf(-x));
    acoef = 0.1f * g; bcoef = 0.9f;
  }

  for (int j4 = tid; j4 < D / 4; j4 += 256) {
    float4 mv = ((const float4*)mrow)[j4];
    float4 vv = make_float4(0.f, 0.f, 0.f, 0.f);
    if (written) vv = ((const float4*)vrow)[j4];
    float ov[4];
    ov[0] = acoef * vv.x + bcoef * mv.x;
    ov[1] = acoef * vv.y + bcoef * mv.y;
    ov[2] = acoef * vv.z + bcoef * mv.z;
    ov[3] = acoef * vv.w + bcoef * mv.w;
    ((float4*)(ws_mem + (size_t)s * D))[j4] =
        make_float4(ov[0], ov[1], ov[2], ov[3]);
    unsigned short h[4], md[4];
#pragma unroll
    for (int e = 0; e < 4; ++e) {
      h[e] = bfrne(ov[e]);
      float f = __uint_as_float((unsigned)h[e] << 16);
      md[e] = bfrne(ov[e] - f);
    }
    uint2 hp = make_uint2((unsigned)h[0] | ((unsigned)h[1] << 16),
                          (unsigned)h[2] | ((unsigned)h[3] << 16));
    uint2 mp = make_uint2((unsigned)md[0] | ((unsigned)md[1] << 16),
                          (unsigned)md[2] | ((unsigned)md[3] << 16));
    ((uint2*)Mh)[(size_t)s * (D / 4) + j4] = hp;
    ((uint2*)Mm)[(size_t)s * (D / 4) + j4] = mp;
#pragma unroll
    for (int e = 0; e < 4; ++e) {
      Mth[(size_t)(j4 * 4 + e) * NSLOTS + s] = h[e];
      Mtm[(size_t)(j4 * 4 + e) * NSLOTS + s] = md[e];
    }
  }
}

// ---- Kernel B: partial scores, tileQ=64 x splitK=8 --------------------------
// grid = (TR/64) * 8 = 1024 blocks x 256 thr. Block (qt,kq): rows qt*64..+64,
// K range kq*512..+512, all 128 slots. Wave w: rows +w*16. No LDS, no barrier.
// part[kq][row][slot] = sum over this K-chunk (unscaled).
__global__ __launch_bounds__(256) void scores_kernel(
    const float* __restrict__ queries, const unsigned short* __restrict__ Mh,
    const unsigned short* __restrict__ Mm, float* __restrict__ part) {
  const int tid = threadIdx.x, lane = tid & 63, w = tid >> 6;
  const int fr = lane & 15, fo = lane >> 4;
  const int qt = blockIdx.x >> 3, kq = blockIdx.x & 7;
  const int row0 = qt * 64 + w * 16;
  const int kbase = kq * 512;

  const float* qp = queries + (size_t)(row0 + fr) * D + kbase + fo * 8;
  const unsigned short* mhp = Mh + (size_t)fr * D + kbase + fo * 8;
  const unsigned short* mmp = Mm + (size_t)fr * D + kbase + fo * 8;

  f32x4 acc[8];
#pragma unroll
  for (int g = 0; g < 8; ++g) acc[g] = (f32x4){0.f, 0.f, 0.f, 0.f};

  for (int k0 = 0; k0 < 512; k0 += 32) {
    float4 qa = *(const float4*)(qp + k0);
    float4 qb = *(const float4*)(qp + k0 + 4);
    float qf[8] = {qa.x, qa.y, qa.z, qa.w, qb.x, qb.y, qb.z, qb.w};
    BV ah, am;
#pragma unroll
    for (int i = 0; i < 4; ++i) {
      unsigned u0 = __float_as_uint(qf[2 * i]);
      unsigned u1 = __float_as_uint(qf[2 * i + 1]);
      ah.u[i] = (u0 >> 16) | (u1 & 0xffff0000u);     // truncated hi
      float f0 = __uint_as_float(u0 & 0xffff0000u);
      float f1 = __uint_as_float(u1 & 0xffff0000u);
      unsigned d0 = __float_as_uint(qf[2 * i] - f0);
      unsigned d1 = __float_as_uint(qf[2 * i + 1] - f1);
      am.u[i] = (d0 >> 16) | (d1 & 0xffff0000u);     // truncated mid
    }
#pragma unroll
    for (int g = 0; g < 8; ++g) {
      bf16x8 bh = *(const bf16x8*)(mhp + (size_t)g * 16 * D + k0);
      bf16x8 bm = *(const bf16x8*)(mmp + (size_t)g * 16 * D + k0);
      acc[g] = __builtin_amdgcn_mfma_f32_16x16x32_bf16(am.v, bh, acc[g], 0, 0, 0);
      acc[g] = __builtin_amdgcn_mfma_f32_16x16x32_bf16(ah.v, bm, acc[g], 0, 0, 0);
      acc[g] = __builtin_amdgcn_mfma_f32_16x16x32_bf16(ah.v, bh, acc[g], 0, 0, 0);
    }
  }

  float* op = part + ((size_t)kq * TR + row0) * NSLOTS;
#pragma unroll
  for (int g = 0; g < 8; ++g)
#pragma unroll
    for (int r = 0; r < 4; ++r)
      op[(size_t)(fo * 4 + r) * NSLOTS + g * 16 + fr] = acc[g][r];
}

// ---- Kernel C: wave-per-row reduce-partials -> top-k -> softmax -> A planes --
__device__ __forceinline__ unsigned mapf(float f) {
  unsigned u = __float_as_uint(f);
  return (u & 0x80000000u) ? ~u : (u | 0x80000000u);
}
__device__ __forceinline__ float unmapf(unsigned u) {
  return __uint_as_float((u & 0x80000000u) ? (u & 0x7fffffffu) : ~u);
}

__device__ __forceinline__ void wave_select(
    float va, float vb, int l, int k, int iters,
    float &m, float &sum, bool &sela, bool &selb, float &vkm1, float &vkk) {
  m = 0.f; sum = 0.f; sela = false; selb = false; vkm1 = 0.f; vkk = -3.4e38f;
  for (int it = 0; it < iters; ++it) {
    unsigned long long ka =
        ((unsigned long long)mapf(va) << 32) | (unsigned)(127 - l);
    unsigned long long kb =
        ((unsigned long long)mapf(vb) << 32) | (unsigned)(63 - l);
    unsigned long long key = ka > kb ? ka : kb;
#pragma unroll
    for (int off = 32; off; off >>= 1) {
      unsigned long long o = __shfl_xor(key, off, 64);
      if (o > key) key = o;
    }
    int idx = 127 - (int)(unsigned)(key & 0xffffffffULL);
    float val = unmapf((unsigned)(key >> 32));
    if (it == 0) m = val;
    if (it < k) sum += expf(val - m);
    if (it == k - 1) vkm1 = val;
    if (it == k) vkk = val;
    if (idx == l) { sela = sela || (it < k); va = -INFINITY; }
    if (idx == l + 64) { selb = selb || (it < k); vb = -INFINITY; }
  }
}

__device__ __forceinline__ float rescore_slot(const float* __restrict__ qrow,
                                              const float* __restrict__ mrow,
                                              int l) {
  double acc = 0.0;
#pragma unroll 4
  for (int c = 0; c < 16; ++c) {
    int j = c * 256 + l * 4;
    float4 qv = *(const float4*)(qrow + j);
    float4 mv = *(const float4*)(mrow + j);
    acc += (double)qv.x * (double)mv.x;
    acc += (double)qv.y * (double)mv.y;
    acc += (double)qv.z * (double)mv.z;
    acc += (double)qv.w * (double)mv.w;
  }
#pragma unroll
  for (int off = 32; off; off >>= 1) acc += __shfl_xor(acc, off, 64);
  return (float)(acc * 0.015625);
}

__global__ __launch_bounds__(256) void topk_kernel(
    const float* __restrict__ part, const float* __restrict__ ws_mem,
    const float* __restrict__ queries, const int* __restrict__ k_p,
    unsigned short* __restrict__ Ah, unsigned short* __restrict__ Am) {
  const int w = threadIdx.x >> 6, l = threadIdx.x & 63;
  const int row = blockIdx.x * 4 + w;
  int k = k_p[0];
  if (k < 1) k = 1;
  if (k > NSLOTS) k = NSLOTS;
  const int ksel = (k < NSLOTS) ? k + 1 : k;

  float origa = 0.f, origb = 0.f;
#pragma unroll
  for (int kq = 0; kq < 8; ++kq) {
    origa += part[((size_t)kq * TR + row) * NSLOTS + l];
    origb += part[((size_t)kq * TR + row) * NSLOTS + 64 + l];
  }
  origa *= 0.015625f;   // 1/sqrt(4096)
  origb *= 0.015625f;

  float m, sum, vkm1, vkk;
  bool sela, selb;
  wave_select(origa, origb, l, k, ksel, m, sum, sela, selb, vkm1, vkk);

  if (ksel > k && (vkm1 - vkk) < EPS_TRIG) {
    // exact fp64 rescore of boundary-window slots only (set membership fix)
    const float* qrow = queries + (size_t)row * D;
    float lo = vkk - WIN, hi = vkm1 + WIN;
    unsigned long long ba = __ballot(origa >= lo && origa <= hi);
    unsigned long long bb = __ballot(origb >= lo && origb <= hi);
    while (ba) {
      int s = __ffsll(ba) - 1; ba &= ba - 1;
      float ex = rescore_slot(qrow, ws_mem + (size_t)s * D, l);
      if (l == s) origa = ex;
    }
    while (bb) {
      int s = __ffsll(bb) - 1; bb &= bb - 1;
      float ex = rescore_slot(qrow, ws_mem + (size_t)(s + 64) * D, l);
      if (l == s) origb = ex;
    }
    wave_select(origa, origb, l, k, k, m, sum, sela, selb, vkm1, vkk);
  }

  const float inv = 1.0f / sum;
  float wa = sela ? expf(origa - m) * inv : 0.f;
  float wb = selb ? expf(origb - m) * inv : 0.f;

  unsigned short ha = bfrne(wa);
  unsigned short ma = bfrne(wa - __uint_as_float((unsigned)ha << 16));
  unsigned short hb = bfrne(wb);
  unsigned short mb = bfrne(wb - __uint_as_float((unsigned)hb << 16));
  Ah[(size_t)row * NSLOTS + l] = ha;
  Am[(size_t)row * NSLOTS + l] = ma;
  Ah[(size_t)row * NSLOTS + 64 + l] = hb;
  Am[(size_t)row * NSLOTS + 64 + l] = mb;
}

// ---- Kernel D: out = A @ mem_new as dense bf16-split GEMM (K=128) ----
__global__ __launch_bounds__(256) void gather_kernel(
    const unsigned short* __restrict__ Ah, const unsigned short* __restrict__ Am,
    const unsigned short* __restrict__ Mth, const unsigned short* __restrict__ Mtm,
    float* __restrict__ out) {
  const int tid = threadIdx.x, lane = tid & 63, w = tid >> 6;
  const int fr = lane & 15, fo = lane >> 4;
  const int rowblk = blockIdx.x >> 5, colblk = blockIdx.x & 31;
  const int r0 = rowblk * 64 + w * 16;

  const unsigned short* ap_h = Ah + (size_t)(r0 + fr) * NSLOTS + fo * 8;
  const unsigned short* ap_m = Am + (size_t)(r0 + fr) * NSLOTS + fo * 8;
  bf16x8 a_h[4], a_m[4];
#pragma unroll
  for (int c = 0; c < 4; ++c) {
    a_h[c] = *(const bf16x8*)(ap_h + c * 32);
    a_m[c] = *(const bf16x8*)(ap_m + c * 32);
  }

#pragma unroll 2
  for (int ct = 0; ct < 8; ++ct) {
    const int col = colblk * 128 + ct * 16 + fr;
    const unsigned short* bp_h = Mth + (size_t)col * NSLOTS + fo * 8;
    const unsigned short* bp_m = Mtm + (size_t)col * NSLOTS + fo * 8;
    f32x4 acc = {0.f, 0.f, 0.f, 0.f};
#pragma unroll
    for (int c = 0; c < 4; ++c) {
      bf16x8 bh = *(const bf16x8*)(bp_h + c * 32);
      bf16x8 bm = *(const bf16x8*)(bp_m + c * 32);
      acc = __builtin_amdgcn_mfma_f32_16x16x32_bf16(a_m[c], bh, acc, 0, 0, 0);
      acc = __builtin_amdgcn_mfma_f32_16x16x32_bf16(a_h[c], bm, acc, 0, 0, 0);
      acc = __builtin_amdgcn_mfma_f32_16x16x32_bf16(a_h[c], bh, acc, 0, 0, 0);
    }
#pragma unroll
    for (int r = 0; r < 4; ++r)
      out[(size_t)(r0 + fo * 4 + r) * D + col] = acc[r];
  }
}

extern "C" void kernel_launch(void* const* d_in, const int* in_sizes, int n_in,
                              void* d_out, int out_size, void* d_ws, size_t ws_size,
                              hipStream_t stream) {
  const float* values  = (const float*)d_in[0];
  const float* queries = (const float*)d_in[1];
  const float* memory  = (const float*)d_in[2];
  const float* gate_w  = (const float*)d_in[3];
  const float* gate_b  = (const float*)d_in[4];
  const int* layer_idx = (const int*)d_in[5];
  const int* k_p       = (const int*)d_in[6];
  const int* ptr_p     = (const int*)d_in[7];

  const int T_W = in_sizes[0] / D;   // 128
  const int T_R = in_sizes[1] / D;   // 8192

  float* ws_mem = (float*)d_ws;                              // 2 MiB
  float* part   = ws_mem + (size_t)NSLOTS * D;               // 8 planes, 32 MiB
  unsigned short* Mh  = (unsigned short*)(part + (size_t)8 * TR * NSLOTS);
  unsigned short* Mm  = Mh  + (size_t)NSLOTS * D;            // 1 MiB each
  unsigned short* Mth = Mm  + (size_t)NSLOTS * D;
  unsigned short* Mtm = Mth + (size_t)NSLOTS * D;
  unsigned short* Ah  = Mtm + (size_t)NSLOTS * D;            // 2 MiB each
  unsigned short* Am  = Ah  + (size_t)T_R * NSLOTS;

  update_mem_kernel<<<NSLOTS, 256, 0, stream>>>(
      values, memory, gate_w, gate_b, layer_idx, ptr_p, T_W,
      ws_mem, Mh, Mm, Mth, Mtm);
  scores_kernel<<<(T_R / 64) * 8, 256, 0, stream>>>(queries, Mh, Mm, part);
  topk_kernel<<<T_R / 4, 256, 0, stream>>>(part, ws_mem, queries, k_p, Ah, Am);
  gather_kernel<<<(T_R / 64) * 32, 256, 0, stream>>>(Ah, Am, Mth, Mtm,
                                                     (float*)d_out);
}